// Round 7
// baseline (45.459 us; speedup 1.0000x reference)
//
#include <hip/hip_runtime.h>
#include <hip/hip_bf16.h>
#include <cstddef>

#define B_ 8
#define C_ 2048
#define E_ 256
#define H_ 64
#define T_ 512
#define NA 4
#define KAPPA 0.9f
#define LOG2_KAPPA (-0.15200309344504997f)   // log2(0.9)
#define KAPPA_T 3.73302e-24f                 // 0.9^512

typedef __attribute__((ext_vector_type(8))) short bf16x8;
typedef __attribute__((ext_vector_type(4))) float f32x4;

__device__ inline short f2bf(float x) {
    unsigned u = __builtin_bit_cast(unsigned, x);
    u += 0x7fff + ((u >> 16) & 1);   // RNE
    return (short)(u >> 16);
}
__device__ inline float bf2f(unsigned short u) {
    return __builtin_bit_cast(float, (unsigned)u << 16);
}

// ---- prep: blocks 0-11 W transpose f32->bf16; blocks 12-19 dones -> s_tab --
// s_tab[b*T+n] = last done timestep <= n, or -1 if none.
__global__ __launch_bounds__(256) void prep_kernel(
    const float* __restrict__ w_q, const float* __restrict__ w_k,
    const float* __restrict__ w_v, short* __restrict__ wt,
    const unsigned char* __restrict__ raw, int* __restrict__ s_tab)
{
    const int t = threadIdx.x;
    if (blockIdx.x < 12) {
        const int mat = blockIdx.x >> 2;
        const int k0  = (blockIdx.x & 3) * 64;
        const float* W = (mat == 0) ? w_q : (mat == 1) ? w_k : w_v;
        __shared__ float tile[64][67];
#pragma unroll
        for (int pass = 0; pass < 16; ++pass) {
            int idx = pass * 256 + t;
            int r = idx >> 6, c = idx & 63;
            tile[r][c] = W[(size_t)(k0 + r) * H_ + c];
        }
        __syncthreads();
#pragma unroll
        for (int pass = 0; pass < 16; ++pass) {
            int idx = pass * 256 + t;
            int d = idx >> 6, c = idx & 63;
            wt[(size_t)mat * (H_ * E_) + (size_t)d * E_ + k0 + c] = f2bf(tile[c][d]);
        }
    } else {
        const int b    = blockIdx.x - 12;
        const int lane = t & 63;
        const int w    = t >> 6;
        // layout detection: bool(1B) vs int32(4B LE 0/1) — full-array scan
        __shared__ int f;
        __shared__ unsigned long long msk[8];
        if (t == 0) f = 0;
        __syncthreads();
        int local = 0;
        for (int j = t; j < B_ * C_; j += 256)
            if ((j & 3) && raw[j]) local = 1;
        if (local) f = 1;
        __syncthreads();
        const int stride = f ? 1 : 4;
        const unsigned char* drow = raw + (size_t)b * C_ * stride;

        // masks: chunk c covers timesteps [64c, 64c+64)
#pragma unroll
        for (int cc = 0; cc < 2; ++cc) {
            const int c = 2 * w + cc;
            const int n = c * 64 + lane;
            unsigned long long m =
                __ballot(drow[(size_t)(4 * n) * stride] != 0);
            if (lane == 0) msk[c] = m;
        }
        __syncthreads();
#pragma unroll
        for (int cc = 0; cc < 2; ++cc) {
            const int c = 2 * w + cc;
            const int n = c * 64 + lane;
            unsigned long long lowmask =
                (lane == 63) ? ~0ULL : ((1ULL << (lane + 1)) - 1ULL);
            unsigned long long m_le = msk[c] & lowmask;
            int s = -1;
            if (m_le) {
                s = c * 64 + (63 - __builtin_clzll(m_le));
            } else {
                for (int c2 = c - 1; c2 >= 0; --c2) {
                    if (msk[c2]) {
                        s = c2 * 64 + (63 - __builtin_clzll(msk[c2]));
                        break;
                    }
                }
            }
            s_tab[b * T_ + n] = s;
        }
    }
}

// ---------------- Projection GEMM via MFMA, barrier-free K loop -------------
// XCD swizzle: batch b = blockIdx.x & 7 pins to XCD b. q -> f32, k/v -> bf16.
__global__ __launch_bounds__(256) void proj_mfma(
    const float* __restrict__ key_in, const float* __restrict__ query,
    const float* __restrict__ value, const short* __restrict__ wt,
    float* __restrict__ qp, unsigned short* __restrict__ kp16,
    unsigned short* __restrict__ vp16)
{
    const int mat = blockIdx.y;
    const float* A;
    if (mat == 0)      A = query;
    else if (mat == 1) A = key_in;
    else               A = value;

    __shared__ short Wt[64][264];  // row stride 528B -> 2-way banks (free)

    const int t    = threadIdx.x;
    const int b    = blockIdx.x & 7;
    const int rb   = blockIdx.x >> 3;
    const int row0 = b * C_ + rb * 64;
    const int lane = t & 63;
    const int mt   = t >> 6;
    const int lr   = lane & 15;
    const int lg   = lane >> 4;

    const short* wsrc = wt + (size_t)mat * (H_ * E_);
#pragma unroll
    for (int pass = 0; pass < 8; ++pass) {
        int idx = pass * 2048 + t * 8;
        int d = idx >> 8, k = idx & 255;
        *(bf16x8*)&Wt[d][k] = *(const bf16x8*)&wsrc[idx];
    }
    __syncthreads();

    const float* arow = &A[(size_t)(row0 + mt * 16 + lr) * E_ + lg * 8];

    f32x4 acc[4] = {};
#pragma unroll
    for (int kc = 0; kc < 8; ++kc) {
        f32x4 x0 = *(const f32x4*)(arow + kc * 32);
        f32x4 x1 = *(const f32x4*)(arow + kc * 32 + 4);
        bf16x8 af;
        af[0] = f2bf(x0[0]); af[1] = f2bf(x0[1]);
        af[2] = f2bf(x0[2]); af[3] = f2bf(x0[3]);
        af[4] = f2bf(x1[0]); af[5] = f2bf(x1[1]);
        af[6] = f2bf(x1[2]); af[7] = f2bf(x1[3]);
#pragma unroll
        for (int nt = 0; nt < 4; ++nt) {
            bf16x8 bfrag = *(const bf16x8*)&Wt[nt * 16 + lr][kc * 32 + lg * 8];
            acc[nt] = __builtin_amdgcn_mfma_f32_16x16x32_bf16(af, bfrag, acc[nt], 0, 0, 0);
        }
    }

    if (mat == 0) {
#pragma unroll
        for (int nt = 0; nt < 4; ++nt)
#pragma unroll
            for (int i = 0; i < 4; ++i)
                qp[(size_t)(row0 + mt * 16 + lg * 4 + i) * H_ + nt * 16 + lr] =
                    acc[nt][i];
    } else {
        unsigned short* O = (mat == 1) ? kp16 : vp16;
#pragma unroll
        for (int nt = 0; nt < 4; ++nt)
#pragma unroll
            for (int i = 0; i < 4; ++i)
                O[(size_t)(row0 + mt * 16 + lg * 4 + i) * H_ + nt * 16 + lr] =
                    (unsigned short)f2bf(acc[nt][i]);
    }
}

// ---------------- out0 + next_h, wave-per-unit, s from table ----------------
// blocks 0..1023 -> out0: b = bid&7 (XCD pin), n = (bid>>3)*4 + wave.
// blocks 1024..1151 -> next_h: b = j&7, h = (j>>3)*4 + wave.
__global__ __launch_bounds__(256) void out_kernel(
    const float* __restrict__ qp, const unsigned short* __restrict__ kp16,
    const unsigned short* __restrict__ vp16, const float* __restrict__ hs,
    const int* __restrict__ s_tab,
    float* __restrict__ out0, float* __restrict__ outh)
{
    const int t    = threadIdx.x;
    const int lane = t & 63;
    const int w    = t >> 6;
    const int bid  = blockIdx.x;

    if (bid < 1024) {
        const int b = bid & 7;
        const int n = (bid >> 3) * 4 + w;
        const int a = lane >> 4;
        const int g = lane & 15;

        const int st = s_tab[b * T_ + n];
        const int s  = (st < 0) ? 0 : st;

        const unsigned short* kb = kp16 + (size_t)b * C_ * H_;
        const unsigned short* vb = vp16 + (size_t)b * C_ * H_;
        f32x4 q4 = *(const f32x4*)&qp[((size_t)b * C_ + 4 * n + a) * H_ + 4 * g];

        f32x4 acc = {};
        // diagonal timestep: decay 1, causal mask ma <= a
#pragma unroll
        for (int ma = 0; ma < NA; ++ma) {
            const int m = 4 * n + ma;
            ushort4 ku = *(const ushort4*)&kb[(size_t)m * H_ + 4 * g];
            float p = q4[0] * bf2f(ku.x) + q4[1] * bf2f(ku.y)
                    + q4[2] * bf2f(ku.z) + q4[3] * bf2f(ku.w);
            p += __shfl_xor(p, 1); p += __shfl_xor(p, 2);
            p += __shfl_xor(p, 4); p += __shfl_xor(p, 8);
            if (ma <= a) {
                ushort4 vu = *(const ushort4*)&vb[(size_t)m * H_ + 4 * g];
                acc[0] += p * bf2f(vu.x); acc[1] += p * bf2f(vu.y);
                acc[2] += p * bf2f(vu.z); acc[3] += p * bf2f(vu.w);
            }
        }
        // earlier timesteps in segment
        float decay = KAPPA;
        for (int mt = n - 1; mt >= s; --mt) {
#pragma unroll
            for (int ma = 0; ma < NA; ++ma) {
                const int m = 4 * mt + ma;
                ushort4 ku = *(const ushort4*)&kb[(size_t)m * H_ + 4 * g];
                float p = q4[0] * bf2f(ku.x) + q4[1] * bf2f(ku.y)
                        + q4[2] * bf2f(ku.z) + q4[3] * bf2f(ku.w);
                p += __shfl_xor(p, 1); p += __shfl_xor(p, 2);
                p += __shfl_xor(p, 4); p += __shfl_xor(p, 8);
                p *= decay;
                ushort4 vu = *(const ushort4*)&vb[(size_t)m * H_ + 4 * g];
                acc[0] += p * bf2f(vu.x); acc[1] += p * bf2f(vu.y);
                acc[2] += p * bf2f(vu.z); acc[3] += p * bf2f(vu.w);
            }
            decay *= KAPPA;
        }
        // cross term (xi != 0 iff no done in [0, n] <=> st < 0)
        if (st < 0) {
            const float xi = exp2f(LOG2_KAPPA * (float)(n + 1));
            const float* hsb = hs + (size_t)b * H_ * H_;
            f32x4 cacc = {};
#pragma unroll
            for (int h = 0; h < H_; ++h) {
                float qh = __shfl(q4[h & 3], (a << 4) + (h >> 2));
                f32x4 h4 = *(const f32x4*)&hsb[h * H_ + 4 * g];
                cacc[0] += qh * h4[0]; cacc[1] += qh * h4[1];
                cacc[2] += qh * h4[2]; cacc[3] += qh * h4[3];
            }
            acc[0] += xi * cacc[0]; acc[1] += xi * cacc[1];
            acc[2] += xi * cacc[2]; acc[3] += xi * cacc[3];
        }
        *(f32x4*)&out0[((size_t)b * C_ + 4 * n + a) * H_ + 4 * g] = acc;
    } else {
        const int j = bid - 1024;            // [0,128)
        const int b = j & 7;
        const int h = (j >> 3) * 4 + w;      // [0,64)
        const int d = lane;

        const int st = s_tab[b * T_ + (T_ - 1)];
        const int s  = (st < 0) ? 0 : st;

        const unsigned short* kb = kp16 + (size_t)b * C_ * H_;
        const unsigned short* vb = vp16 + (size_t)b * C_ * H_;
        float acc = 0.f, wdec = 1.f;
        for (int mt = T_ - 1; mt >= s; --mt) {
#pragma unroll
            for (int ma = 0; ma < NA; ++ma) {
                const int m = 4 * mt + ma;
                acc += wdec * bf2f(kb[(size_t)m * H_ + h]) *
                              bf2f(vb[(size_t)m * H_ + d]);
            }
            wdec *= KAPPA;
        }
        if (st < 0)
            acc += hs[((size_t)b * H_ + h) * H_ + d] * KAPPA_T;
        outh[((size_t)b * H_ + h) * H_ + d] = acc;
    }
}

extern "C" void kernel_launch(void* const* d_in, const int* in_sizes, int n_in,
                              void* d_out, int out_size, void* d_ws, size_t ws_size,
                              hipStream_t stream)
{
    const float* key_in = (const float*)d_in[0];
    const float* query  = (const float*)d_in[1];
    const float* value  = (const float*)d_in[2];
    const float* hstate = (const float*)d_in[3];
    const unsigned char* dones = (const unsigned char*)d_in[4];
    const float* w_q = (const float*)d_in[5];
    const float* w_k = (const float*)d_in[6];
    const float* w_v = (const float*)d_in[7];

    unsigned short* kp16 = (unsigned short*)d_ws;
    unsigned short* vp16 = kp16 + (size_t)B_ * C_ * H_;
    float*          qp   = (float*)(vp16 + (size_t)B_ * C_ * H_);
    short*          wt   = (short*)(qp + (size_t)B_ * C_ * H_);
    int*            s_tab = (int*)(wt + 3 * H_ * E_);

    prep_kernel<<<20, 256, 0, stream>>>(w_q, w_k, w_v, wt, dones, s_tab);
    dim3 pgrid(B_ * C_ / 64, 3);
    proj_mfma<<<pgrid, 256, 0, stream>>>(key_in, query, value, wt, qp, kp16, vp16);
    out_kernel<<<1024 + 128, 256, 0, stream>>>(
        qp, kp16, vp16, hstate, s_tab,
        (float*)d_out, (float*)d_out + (size_t)B_ * C_ * H_);
}

// Round 8
// 30.860 us; speedup vs baseline: 1.4731x; 1.4731x over previous
//
#include <hip/hip_runtime.h>
#include <hip/hip_bf16.h>
#include <cstddef>

#define B_ 8
#define C_ 2048
#define E_ 256
#define H_ 64
#define T_ 512
#define NA 4
#define KAPPA 0.9f
#define LOG2_KAPPA (-0.15200309344504997f)   // log2(0.9)
#define KAPPA_T 3.73302e-24f                 // 0.9^512

typedef __attribute__((ext_vector_type(8))) short bf16x8;
typedef __attribute__((ext_vector_type(4))) float f32x4;

__device__ inline short f2bf(float x) {
    unsigned u = __builtin_bit_cast(unsigned, x);
    u += 0x7fff + ((u >> 16) & 1);   // RNE
    return (short)(u >> 16);
}

// ---- prep: blocks 0-11 W transpose f32->bf16; blocks 12-19 dones -> s_tab --
// s_tab[b*T+n] = last done timestep <= n, or -1 if none.
__global__ __launch_bounds__(256) void prep_kernel(
    const float* __restrict__ w_q, const float* __restrict__ w_k,
    const float* __restrict__ w_v, short* __restrict__ wt,
    const unsigned char* __restrict__ raw, int* __restrict__ s_tab)
{
    const int t = threadIdx.x;
    if (blockIdx.x < 12) {
        const int mat = blockIdx.x >> 2;
        const int k0  = (blockIdx.x & 3) * 64;
        const float* W = (mat == 0) ? w_q : (mat == 1) ? w_k : w_v;
        __shared__ float tile[64][67];
#pragma unroll
        for (int pass = 0; pass < 16; ++pass) {
            int idx = pass * 256 + t;
            int r = idx >> 6, c = idx & 63;
            tile[r][c] = W[(size_t)(k0 + r) * H_ + c];
        }
        __syncthreads();
#pragma unroll
        for (int pass = 0; pass < 16; ++pass) {
            int idx = pass * 256 + t;
            int d = idx >> 6, c = idx & 63;
            wt[(size_t)mat * (H_ * E_) + (size_t)d * E_ + k0 + c] = f2bf(tile[c][d]);
        }
    } else {
        const int b    = blockIdx.x - 12;
        const int lane = t & 63;
        const int w    = t >> 6;
        // layout detection: bool(1B) vs int32(4B LE 0/1). Vectorized prefix
        // scan of the first B_*C_ bytes; int32 layout has all %4!=0 bytes
        // zero everywhere, so a prefix scan cannot false-positive.
        __shared__ int f;
        __shared__ unsigned long long msk[8];
        if (t == 0) f = 0;
        __syncthreads();
        {
            const uint4* dp = (const uint4*)raw;
            unsigned acc = 0;
#pragma unroll
            for (int i = 0; i < 4; ++i) {
                uint4 v = dp[t + 256 * i];   // covers 16KB = B_*C_ bytes
                acc |= (v.x | v.y | v.z | v.w) & 0xFFFFFF00u;
            }
            if (acc) f = 1;
        }
        __syncthreads();
        const int stride = f ? 1 : 4;
        const unsigned char* drow = raw + (size_t)b * C_ * stride;

        // masks: chunk c covers timesteps [64c, 64c+64)
#pragma unroll
        for (int cc = 0; cc < 2; ++cc) {
            const int c = 2 * w + cc;
            const int n = c * 64 + lane;
            unsigned long long m =
                __ballot(drow[(size_t)(4 * n) * stride] != 0);
            if (lane == 0) msk[c] = m;
        }
        __syncthreads();
#pragma unroll
        for (int cc = 0; cc < 2; ++cc) {
            const int c = 2 * w + cc;
            const int n = c * 64 + lane;
            unsigned long long lowmask =
                (lane == 63) ? ~0ULL : ((1ULL << (lane + 1)) - 1ULL);
            unsigned long long m_le = msk[c] & lowmask;
            int s = -1;
            if (m_le) {
                s = c * 64 + (63 - __builtin_clzll(m_le));
            } else {
                for (int c2 = c - 1; c2 >= 0; --c2) {
                    if (msk[c2]) {
                        s = c2 * 64 + (63 - __builtin_clzll(msk[c2]));
                        break;
                    }
                }
            }
            s_tab[b * T_ + n] = s;
        }
    }
}

// ---------------- Projection GEMM via MFMA, barrier-free K loop -------------
// XCD swizzle: batch b = blockIdx.x & 7 pins to XCD b (256 x-blocks, %8 stable
// across the y-dim since 256%8==0). All outputs f32 (dword stores).
__global__ __launch_bounds__(256) void proj_mfma(
    const float* __restrict__ key_in, const float* __restrict__ query,
    const float* __restrict__ value, const short* __restrict__ wt,
    float* __restrict__ qp, float* __restrict__ kp, float* __restrict__ vp)
{
    const int mat = blockIdx.y;
    const float* A; float* O;
    if (mat == 0)      { A = query;  O = qp; }
    else if (mat == 1) { A = key_in; O = kp; }
    else               { A = value;  O = vp; }

    __shared__ short Wt[64][264];  // row stride 528B -> 2-way banks (free)

    const int t    = threadIdx.x;
    const int b    = blockIdx.x & 7;
    const int rb   = blockIdx.x >> 3;
    const int row0 = b * C_ + rb * 64;
    const int lane = t & 63;
    const int mt   = t >> 6;
    const int lr   = lane & 15;
    const int lg   = lane >> 4;

    const short* wsrc = wt + (size_t)mat * (H_ * E_);
#pragma unroll
    for (int pass = 0; pass < 8; ++pass) {
        int idx = pass * 2048 + t * 8;
        int d = idx >> 8, k = idx & 255;
        *(bf16x8*)&Wt[d][k] = *(const bf16x8*)&wsrc[idx];
    }
    __syncthreads();

    const float* arow = &A[(size_t)(row0 + mt * 16 + lr) * E_ + lg * 8];

    f32x4 acc[4] = {};
#pragma unroll
    for (int kc = 0; kc < 8; ++kc) {
        f32x4 x0 = *(const f32x4*)(arow + kc * 32);
        f32x4 x1 = *(const f32x4*)(arow + kc * 32 + 4);
        bf16x8 af;
        af[0] = f2bf(x0[0]); af[1] = f2bf(x0[1]);
        af[2] = f2bf(x0[2]); af[3] = f2bf(x0[3]);
        af[4] = f2bf(x1[0]); af[5] = f2bf(x1[1]);
        af[6] = f2bf(x1[2]); af[7] = f2bf(x1[3]);
#pragma unroll
        for (int nt = 0; nt < 4; ++nt) {
            bf16x8 bfrag = *(const bf16x8*)&Wt[nt * 16 + lr][kc * 32 + lg * 8];
            acc[nt] = __builtin_amdgcn_mfma_f32_16x16x32_bf16(af, bfrag, acc[nt], 0, 0, 0);
        }
    }

#pragma unroll
    for (int nt = 0; nt < 4; ++nt)
#pragma unroll
        for (int i = 0; i < 4; ++i)
            O[(size_t)(row0 + mt * 16 + lg * 4 + i) * H_ + nt * 16 + lr] = acc[nt][i];
}

// ---------------- out0 + next_h, wave-per-unit, s from table ----------------
// blocks 0..1023 -> out0: b = bid&7 (XCD pin), n = (bid>>3)*4 + wave.
// blocks 1024..1151 -> next_h: b = j&7, h = (j>>3)*4 + wave.
__global__ __launch_bounds__(256) void out_kernel(
    const float* __restrict__ qp, const float* __restrict__ kp,
    const float* __restrict__ vp, const float* __restrict__ hs,
    const int* __restrict__ s_tab,
    float* __restrict__ out0, float* __restrict__ outh)
{
    const int t    = threadIdx.x;
    const int lane = t & 63;
    const int w    = t >> 6;
    const int bid  = blockIdx.x;

    if (bid < 1024) {
        const int b = bid & 7;
        const int n = (bid >> 3) * 4 + w;
        const int a = lane >> 4;
        const int g = lane & 15;

        const int st = s_tab[b * T_ + n];
        const int s  = (st < 0) ? 0 : st;

        const float* kb = kp + (size_t)b * C_ * H_;
        const float* vb = vp + (size_t)b * C_ * H_;
        f32x4 q4 = *(const f32x4*)&qp[((size_t)b * C_ + 4 * n + a) * H_ + 4 * g];

        f32x4 acc = {};
        // diagonal timestep: decay 1, causal mask ma <= a
#pragma unroll
        for (int ma = 0; ma < NA; ++ma) {
            const int m = 4 * n + ma;
            f32x4 k4 = *(const f32x4*)&kb[(size_t)m * H_ + 4 * g];
            float p = q4[0] * k4[0] + q4[1] * k4[1] + q4[2] * k4[2] + q4[3] * k4[3];
            p += __shfl_xor(p, 1); p += __shfl_xor(p, 2);
            p += __shfl_xor(p, 4); p += __shfl_xor(p, 8);
            if (ma <= a) {
                f32x4 v4 = *(const f32x4*)&vb[(size_t)m * H_ + 4 * g];
                acc[0] += p * v4[0]; acc[1] += p * v4[1];
                acc[2] += p * v4[2]; acc[3] += p * v4[3];
            }
        }
        // earlier timesteps in segment
        float decay = KAPPA;
        for (int mt = n - 1; mt >= s; --mt) {
#pragma unroll
            for (int ma = 0; ma < NA; ++ma) {
                const int m = 4 * mt + ma;
                f32x4 k4 = *(const f32x4*)&kb[(size_t)m * H_ + 4 * g];
                float p = q4[0] * k4[0] + q4[1] * k4[1] + q4[2] * k4[2] + q4[3] * k4[3];
                p += __shfl_xor(p, 1); p += __shfl_xor(p, 2);
                p += __shfl_xor(p, 4); p += __shfl_xor(p, 8);
                p *= decay;
                f32x4 v4 = *(const f32x4*)&vb[(size_t)m * H_ + 4 * g];
                acc[0] += p * v4[0]; acc[1] += p * v4[1];
                acc[2] += p * v4[2]; acc[3] += p * v4[3];
            }
            decay *= KAPPA;
        }
        // cross term (xi != 0 iff no done in [0, n] <=> st < 0)
        if (st < 0) {
            const float xi = exp2f(LOG2_KAPPA * (float)(n + 1));
            const float* hsb = hs + (size_t)b * H_ * H_;
            f32x4 cacc = {};
#pragma unroll
            for (int h = 0; h < H_; ++h) {
                float qh = __shfl(q4[h & 3], (a << 4) + (h >> 2));
                f32x4 h4 = *(const f32x4*)&hsb[h * H_ + 4 * g];
                cacc[0] += qh * h4[0]; cacc[1] += qh * h4[1];
                cacc[2] += qh * h4[2]; cacc[3] += qh * h4[3];
            }
            acc[0] += xi * cacc[0]; acc[1] += xi * cacc[1];
            acc[2] += xi * cacc[2]; acc[3] += xi * cacc[3];
        }
        *(f32x4*)&out0[((size_t)b * C_ + 4 * n + a) * H_ + 4 * g] = acc;
    } else {
        const int j = bid - 1024;            // [0,128)
        const int b = j & 7;
        const int h = (j >> 3) * 4 + w;      // [0,64)
        const int d = lane;

        const int st = s_tab[b * T_ + (T_ - 1)];
        const int s  = (st < 0) ? 0 : st;

        const float* kb = kp + (size_t)b * C_ * H_;
        const float* vb = vp + (size_t)b * C_ * H_;
        float acc = 0.f, wdec = 1.f;
        for (int mt = T_ - 1; mt >= s; --mt) {
#pragma unroll
            for (int ma = 0; ma < NA; ++ma) {
                const int m = 4 * mt + ma;
                acc += wdec * kb[(size_t)m * H_ + h] * vb[(size_t)m * H_ + d];
            }
            wdec *= KAPPA;
        }
        if (st < 0)
            acc += hs[((size_t)b * H_ + h) * H_ + d] * KAPPA_T;
        outh[((size_t)b * H_ + h) * H_ + d] = acc;
    }
}

extern "C" void kernel_launch(void* const* d_in, const int* in_sizes, int n_in,
                              void* d_out, int out_size, void* d_ws, size_t ws_size,
                              hipStream_t stream)
{
    const float* key_in = (const float*)d_in[0];
    const float* query  = (const float*)d_in[1];
    const float* value  = (const float*)d_in[2];
    const float* hstate = (const float*)d_in[3];
    const unsigned char* dones = (const unsigned char*)d_in[4];
    const float* w_q = (const float*)d_in[5];
    const float* w_k = (const float*)d_in[6];
    const float* w_v = (const float*)d_in[7];

    float* qp = (float*)d_ws;
    float* kp = qp + (size_t)B_ * C_ * H_;
    float* vp = kp + (size_t)B_ * C_ * H_;
    short* wt = (short*)(vp + (size_t)B_ * C_ * H_);
    int*   s_tab = (int*)(wt + 3 * H_ * E_);

    prep_kernel<<<20, 256, 0, stream>>>(w_q, w_k, w_v, wt, dones, s_tab);
    dim3 pgrid(B_ * C_ / 64, 3);
    proj_mfma<<<pgrid, 256, 0, stream>>>(key_in, query, value, wt, qp, kp, vp);
    out_kernel<<<1024 + 128, 256, 0, stream>>>(
        qp, kp, vp, hstate, s_tab,
        (float*)d_out, (float*)d_out + (size_t)B_ * C_ * H_);
}